// Round 5
// baseline (97.374 us; speedup 1.0000x reference)
//
#include <hip/hip_runtime.h>
#include <hip/hip_bf16.h>
#include <math.h>

#define N 4096

typedef float f4 __attribute__((ext_vector_type(4)));

// ---------------------------------------------------------------------------
// Fused kernel: a = U@z + V@x (complex matvec) + closed-form Hopf ODE.
//
// Round-5 change: ONE WAVE PER HALF-ROW -> 8192 waves = 32 waves/CU (was 16).
// Tests the MLP theory: HBM fetch sat at 2.73 TB/s with only 16 waves/CU of
// outstanding misses; doubling resident waves should raise it toward 5 TB/s.
// __launch_bounds__(256,8) caps VGPR at 64 so 8 waves/SIMD actually fit
// (round-4 body was 52 VGPR).
//
// Matrix loads NON-TEMPORAL (no L2/L3 allocate -> no thrash; round-4 showed
// 2x from this). Vector loads cached (L1/L2-hot, shared across all rows).
//
// Closed form: dz/dt = (a - |z|^2) z, z = sqrt(u) e^{i th}:
//   th(T) = th0 + Im(a) T (exact); u' = 2(Re(a)-u)u -> logistic (exact).
// Matches the reference's fixed-step DOPRI5 (h=2pi/256) to ~1e-6.
// ---------------------------------------------------------------------------
__global__ __launch_bounds__(256, 8) void fused_kernel(
    const float* __restrict__ Ur, const float* __restrict__ Ui,
    const float* __restrict__ Vr, const float* __restrict__ Vi,
    const float* __restrict__ zr, const float* __restrict__ zi,
    const float* __restrict__ xr, const float* __restrict__ xi,
    float* __restrict__ out)
{
    const int lane = threadIdx.x & 63;
    const int wav  = threadIdx.x >> 6;          // 0..3
    const int row  = (blockIdx.x << 1) | (wav >> 1);   // 2 rows per block
    const int half = wav & 1;                   // column half owned by this wave
    const size_t rbase = (size_t)row * (N / 4);

    const f4* ur4 = (const f4*)Ur + rbase;
    const f4* ui4 = (const f4*)Ui + rbase;
    const f4* vr4 = (const f4*)Vr + rbase;
    const f4* vi4 = (const f4*)Vi + rbase;
    const f4* zr4 = (const f4*)zr;
    const f4* zi4 = (const f4*)zi;
    const f4* xr4 = (const f4*)xr;
    const f4* xi4 = (const f4*)xi;

    f4 sr4 = {0.f, 0.f, 0.f, 0.f};
    f4 si4 = {0.f, 0.f, 0.f, 0.f};

    // 8 chunks of 64 float4 per half-row
    #pragma unroll 4
    for (int k = 0; k < 8; ++k) {
        const int f = (half * 8 + k) * 64 + lane;
        const f4 ur = __builtin_nontemporal_load(ur4 + f);
        const f4 ui = __builtin_nontemporal_load(ui4 + f);
        const f4 vr = __builtin_nontemporal_load(vr4 + f);
        const f4 vi = __builtin_nontemporal_load(vi4 + f);
        const f4 zv = zr4[f];
        const f4 wv = zi4[f];
        const f4 xv = xr4[f];
        const f4 yv = xi4[f];
        sr4 += ur * zv - ui * wv + vr * xv - vi * yv;
        si4 += ur * wv + ui * zv + vr * yv + vi * xv;
    }

    float sr = sr4.x + sr4.y + sr4.z + sr4.w;
    float si = si4.x + si4.y + si4.z + si4.w;

    #pragma unroll
    for (int off = 32; off > 0; off >>= 1) {
        sr += __shfl_xor(sr, off);
        si += __shfl_xor(si, off);
    }

    // combine the two half-row partials via LDS
    __shared__ float pr[4], pi[4];
    if (lane == 0) { pr[wav] = sr; pi[wav] = si; }
    __syncthreads();

    if (threadIdx.x < 2) {
        const int r   = (blockIdx.x << 1) | (int)threadIdx.x;
        const float ar = pr[2 * threadIdx.x] + pr[2 * threadIdx.x + 1];
        const float ai = pi[2 * threadIdx.x] + pi[2 * threadIdx.x + 1];

        const float T  = 6.283185307179586f;
        const float z0r = zr[r];
        const float z0i = zi[r];
        const float u0  = z0r * z0r + z0i * z0i;

        float outr, outi;
        if (u0 == 0.0f) {
            outr = 0.0f; outi = 0.0f;     // fixed point
        } else {
            float ratio;                   // u(T)/u0
            if (fabsf(ar) < 1e-20f) {
                ratio = 1.0f / (1.0f + 2.0f * u0 * T);
            } else if (ar > 0.0f) {
                const float En = expf(-2.0f * ar * T);
                ratio = ar / (ar * En + u0 * (1.0f - En));
            } else {
                const float E = expf(2.0f * ar * T);
                ratio = ar * E / (ar + u0 * (E - 1.0f));
            }
            const float scale = sqrtf(ratio);
            const float th = ai * T;
            const float c = cosf(th);
            const float s = sinf(th);
            outr = (z0r * c - z0i * s) * scale;
            outi = (z0r * s + z0i * c) * scale;
        }
        out[r]     = outr;   // real part -> out[0, :, 0]
        out[N + r] = outi;   // imag part -> out[1, :, 0]
    }
}

extern "C" void kernel_launch(void* const* d_in, const int* in_sizes, int n_in,
                              void* d_out, int out_size, void* d_ws, size_t ws_size,
                              hipStream_t stream)
{
    const float* x_re = (const float*)d_in[0];
    const float* x_im = (const float*)d_in[1];
    const float* z_re = (const float*)d_in[2];
    const float* z_im = (const float*)d_in[3];
    const float* U_re = (const float*)d_in[4];
    const float* U_im = (const float*)d_in[5];
    const float* V_re = (const float*)d_in[6];
    const float* V_im = (const float*)d_in[7];

    float* out = (float*)d_out;

    fused_kernel<<<N / 2, 256, 0, stream>>>(U_re, U_im, V_re, V_im,
                                            z_re, z_im, x_re, x_im, out);
}

// Round 6
// 50.260 us; speedup vs baseline: 1.9374x; 1.9374x over previous
//
#include <hip/hip_runtime.h>
#include <hip/hip_bf16.h>
#include <math.h>

#define N 4096

typedef float f4 __attribute__((ext_vector_type(4)));

// ---------------------------------------------------------------------------
// Fused kernel: a = U@z + V@x (complex matvec) + closed-form Hopf ODE.
//
// Round-6: ONE WAVE PER HALF-ROW (8192 waves = 32/CU) with PLAIN
// __launch_bounds__(256). Round 5's (256,8) min-wave hint made the compiler
// clamp to 32 VGPR and spill to scratch (WRITE_SIZE 98 MB, FETCH +90 MB).
// The body needs ~52 VGPR; 8 waves/SIMD x 52 = 416 <= 512, so 32 waves/CU
// fit WITHOUT any cap — round 4 was merely grid-limited (4096 waves).
// This is the clean MLP test: 2x resident waves, zero spill.
//
// Matrix loads NON-TEMPORAL (no L2/L3 allocate; round 4 showed 2x).
// Vector loads cached (L1/L2-hot, shared across all rows).
//
// Closed form: dz/dt = (a - |z|^2) z, z = sqrt(u) e^{i th}:
//   th(T) = th0 + Im(a) T (exact); u' = 2(Re(a)-u)u -> logistic (exact).
// Matches the reference's fixed-step DOPRI5 (h=2pi/256) to ~1e-6.
// ---------------------------------------------------------------------------
__global__ __launch_bounds__(256) void fused_kernel(
    const float* __restrict__ Ur, const float* __restrict__ Ui,
    const float* __restrict__ Vr, const float* __restrict__ Vi,
    const float* __restrict__ zr, const float* __restrict__ zi,
    const float* __restrict__ xr, const float* __restrict__ xi,
    float* __restrict__ out)
{
    const int lane = threadIdx.x & 63;
    const int wav  = threadIdx.x >> 6;                 // 0..3
    const int row  = (blockIdx.x << 1) | (wav >> 1);   // 2 rows per block
    const int half = wav & 1;                          // column half of this wave
    const size_t rbase = (size_t)row * (N / 4);

    const f4* ur4 = (const f4*)Ur + rbase;
    const f4* ui4 = (const f4*)Ui + rbase;
    const f4* vr4 = (const f4*)Vr + rbase;
    const f4* vi4 = (const f4*)Vi + rbase;
    const f4* zr4 = (const f4*)zr;
    const f4* zi4 = (const f4*)zi;
    const f4* xr4 = (const f4*)xr;
    const f4* xi4 = (const f4*)xi;

    f4 sr4 = {0.f, 0.f, 0.f, 0.f};
    f4 si4 = {0.f, 0.f, 0.f, 0.f};

    // 8 chunks of 64 float4 per half-row
    #pragma unroll 4
    for (int k = 0; k < 8; ++k) {
        const int f = (half * 8 + k) * 64 + lane;
        const f4 ur = __builtin_nontemporal_load(ur4 + f);
        const f4 ui = __builtin_nontemporal_load(ui4 + f);
        const f4 vr = __builtin_nontemporal_load(vr4 + f);
        const f4 vi = __builtin_nontemporal_load(vi4 + f);
        const f4 zv = zr4[f];
        const f4 wv = zi4[f];
        const f4 xv = xr4[f];
        const f4 yv = xi4[f];
        sr4 += ur * zv - ui * wv + vr * xv - vi * yv;
        si4 += ur * wv + ui * zv + vr * yv + vi * xv;
    }

    float sr = sr4.x + sr4.y + sr4.z + sr4.w;
    float si = si4.x + si4.y + si4.z + si4.w;

    #pragma unroll
    for (int off = 32; off > 0; off >>= 1) {
        sr += __shfl_xor(sr, off);
        si += __shfl_xor(si, off);
    }

    // combine the two half-row partials via LDS
    __shared__ float pr[4], pi[4];
    if (lane == 0) { pr[wav] = sr; pi[wav] = si; }
    __syncthreads();

    if (threadIdx.x < 2) {
        const int r    = (blockIdx.x << 1) | (int)threadIdx.x;
        const float ar = pr[2 * threadIdx.x] + pr[2 * threadIdx.x + 1];
        const float ai = pi[2 * threadIdx.x] + pi[2 * threadIdx.x + 1];

        const float T   = 6.283185307179586f;
        const float z0r = zr[r];
        const float z0i = zi[r];
        const float u0  = z0r * z0r + z0i * z0i;

        float outr, outi;
        if (u0 == 0.0f) {
            outr = 0.0f; outi = 0.0f;     // fixed point
        } else {
            float ratio;                   // u(T)/u0
            if (fabsf(ar) < 1e-20f) {
                ratio = 1.0f / (1.0f + 2.0f * u0 * T);
            } else if (ar > 0.0f) {
                const float En = expf(-2.0f * ar * T);
                ratio = ar / (ar * En + u0 * (1.0f - En));
            } else {
                const float E = expf(2.0f * ar * T);
                ratio = ar * E / (ar + u0 * (E - 1.0f));
            }
            const float scale = sqrtf(ratio);
            const float th = ai * T;
            const float c  = cosf(th);
            const float s  = sinf(th);
            outr = (z0r * c - z0i * s) * scale;
            outi = (z0r * s + z0i * c) * scale;
        }
        out[r]     = outr;   // real part -> out[0, :, 0]
        out[N + r] = outi;   // imag part -> out[1, :, 0]
    }
}

extern "C" void kernel_launch(void* const* d_in, const int* in_sizes, int n_in,
                              void* d_out, int out_size, void* d_ws, size_t ws_size,
                              hipStream_t stream)
{
    const float* x_re = (const float*)d_in[0];
    const float* x_im = (const float*)d_in[1];
    const float* z_re = (const float*)d_in[2];
    const float* z_im = (const float*)d_in[3];
    const float* U_re = (const float*)d_in[4];
    const float* U_im = (const float*)d_in[5];
    const float* V_re = (const float*)d_in[6];
    const float* V_im = (const float*)d_in[7];

    float* out = (float*)d_out;

    fused_kernel<<<N / 2, 256, 0, stream>>>(U_re, U_im, V_re, V_im,
                                            z_re, z_im, x_re, x_im, out);
}

// Round 7
// 48.925 us; speedup vs baseline: 1.9903x; 1.0273x over previous
//
#include <hip/hip_runtime.h>
#include <hip/hip_bf16.h>
#include <math.h>

#define N 4096

typedef float f4 __attribute__((ext_vector_type(4)));

// ---------------------------------------------------------------------------
// Fused kernel: a = U@z + V@x (complex matvec) + closed-form Hopf ODE.
//
// Round-7: round-4 base (wave-per-row, 4096 waves = 16/CU — the best
// measured config, 48.6 us) + EXPLICIT depth-1+ software pipeline: chunk
// k+1's four nt matrix loads are issued through named registers before
// chunk k's consume, fully unrolled so the scheduler sees the whole chain.
// Tests the last untested limiter (compiler scheduling depth). Round 4 vs 6
// showed the beyond-L2 read rate (~5.4 TB/s = 2.7 HBM + 2.7 L3) is
// invariant to 16 vs 32 waves/CU -> fabric-limited model; if this lands
// flat at ~48 us, that model stands and we are at the roofline.
//
// Matrix loads NON-TEMPORAL (bypass L2 allocate; rounds 1-3 proved the
// L2-allocating path caps at 2.85 TB/s, nt doubled it). Vector loads
// cached (L1/L2-hot, reused by all rows).
//
// Closed form: dz/dt = (a - |z|^2) z, z = sqrt(u) e^{i th}:
//   th(T) = th0 + Im(a) T (exact); u' = 2(Re(a)-u)u -> logistic (exact).
// Matches the reference's fixed-step DOPRI5 (h=2pi/256) to ~1e-6
// (measured absmax 3.9e-3 vs threshold 5.1e-2).
// ---------------------------------------------------------------------------
__global__ __launch_bounds__(256) void fused_kernel(
    const float* __restrict__ Ur, const float* __restrict__ Ui,
    const float* __restrict__ Vr, const float* __restrict__ Vi,
    const float* __restrict__ zr, const float* __restrict__ zi,
    const float* __restrict__ xr, const float* __restrict__ xi,
    float* __restrict__ out)
{
    const int lane = threadIdx.x & 63;
    const int row  = (blockIdx.x << 2) | (threadIdx.x >> 6);   // wave id
    const size_t rbase = (size_t)row * (N / 4);

    const f4* ur4 = (const f4*)Ur + rbase;
    const f4* ui4 = (const f4*)Ui + rbase;
    const f4* vr4 = (const f4*)Vr + rbase;
    const f4* vi4 = (const f4*)Vi + rbase;
    const f4* zr4 = (const f4*)zr;
    const f4* zi4 = (const f4*)zi;
    const f4* xr4 = (const f4*)xr;
    const f4* xi4 = (const f4*)xi;

    f4 sr4 = {0.f, 0.f, 0.f, 0.f};
    f4 si4 = {0.f, 0.f, 0.f, 0.f};

    // ---- explicit software pipeline: prefetch chunk k+1 while consuming k
    f4 p_ur = __builtin_nontemporal_load(ur4 + lane);
    f4 p_ui = __builtin_nontemporal_load(ui4 + lane);
    f4 p_vr = __builtin_nontemporal_load(vr4 + lane);
    f4 p_vi = __builtin_nontemporal_load(vi4 + lane);

    #pragma unroll
    for (int k = 0; k < 16; ++k) {
        const f4 ur = p_ur, ui = p_ui, vr = p_vr, vi = p_vi;
        if (k + 1 < 16) {
            const int fn = (k + 1) * 64 + lane;
            p_ur = __builtin_nontemporal_load(ur4 + fn);
            p_ui = __builtin_nontemporal_load(ui4 + fn);
            p_vr = __builtin_nontemporal_load(vr4 + fn);
            p_vi = __builtin_nontemporal_load(vi4 + fn);
        }
        const int f = k * 64 + lane;
        const f4 zv = zr4[f];
        const f4 wv = zi4[f];
        const f4 xv = xr4[f];
        const f4 yv = xi4[f];
        sr4 += ur * zv - ui * wv + vr * xv - vi * yv;
        si4 += ur * wv + ui * zv + vr * yv + vi * xv;
    }

    float sr = sr4.x + sr4.y + sr4.z + sr4.w;
    float si = si4.x + si4.y + si4.z + si4.w;

    // butterfly reduce across the 64-lane wave
    #pragma unroll
    for (int off = 32; off > 0; off >>= 1) {
        sr += __shfl_xor(sr, off);
        si += __shfl_xor(si, off);
    }

    if (lane == 0) {
        const float T   = 6.283185307179586f;
        const float ar  = sr;              // Re(a)
        const float ai  = si;              // Im(a)
        const float z0r = zr[row];
        const float z0i = zi[row];
        const float u0  = z0r * z0r + z0i * z0i;

        float outr, outi;
        if (u0 == 0.0f) {
            outr = 0.0f; outi = 0.0f;      // fixed point
        } else {
            float ratio;                    // u(T)/u0
            if (fabsf(ar) < 1e-20f) {
                ratio = 1.0f / (1.0f + 2.0f * u0 * T);
            } else if (ar > 0.0f) {
                const float En = expf(-2.0f * ar * T);
                ratio = ar / (ar * En + u0 * (1.0f - En));
            } else {
                const float E = expf(2.0f * ar * T);
                ratio = ar * E / (ar + u0 * (E - 1.0f));
            }
            const float scale = sqrtf(ratio);
            const float th = ai * T;
            const float c  = cosf(th);
            const float s  = sinf(th);
            outr = (z0r * c - z0i * s) * scale;
            outi = (z0r * s + z0i * c) * scale;
        }
        out[row]     = outr;   // real part -> out[0, :, 0]
        out[N + row] = outi;   // imag part -> out[1, :, 0]
    }
}

extern "C" void kernel_launch(void* const* d_in, const int* in_sizes, int n_in,
                              void* d_out, int out_size, void* d_ws, size_t ws_size,
                              hipStream_t stream)
{
    const float* x_re = (const float*)d_in[0];
    const float* x_im = (const float*)d_in[1];
    const float* z_re = (const float*)d_in[2];
    const float* z_im = (const float*)d_in[3];
    const float* U_re = (const float*)d_in[4];
    const float* U_im = (const float*)d_in[5];
    const float* V_re = (const float*)d_in[6];
    const float* V_im = (const float*)d_in[7];

    float* out = (float*)d_out;

    fused_kernel<<<N / 4, 256, 0, stream>>>(U_re, U_im, V_re, V_im,
                                            z_re, z_im, x_re, x_im, out);
}